// Round 10
// baseline (1738.574 us; speedup 1.0000x reference)
//
#include <hip/hip_runtime.h>
#include <math.h>

// ---------------- problem constants ----------------
#define NTOK   1024      // B*T
#define EXP    16
#define TOPK   4
#define DMODEL 2048
#define DFFN   3584
#define HT_TILES 56      // DFFN/64  (64 H per block: 4 waves x 16)
#define CT_TILES 32      // DMODEL/64 (64 C per block)
#define NSLOT  4096      // NTOK*TOPK, always exactly filled
#define MCH    64        // M-chunk rows (per wave = per block)
#define NCHMAX 80        // max sum of ceil(n_e/64) = 79, padded

typedef __attribute__((ext_vector_type(8))) short bf16x8;
typedef __attribute__((ext_vector_type(4))) float f32x4;

// ---------------- workspace layout (bytes) ----------------
#define O_COUNTS 0
#define O_BASE   256
#define O_CURSOR 512
#define O_CHT    1024                               // int[1+NCHMAX] chunk table
#define O_TOPI   4096
#define O_TOPW   (O_TOPI + 16384)
#define O_TOK    (O_TOPW + 16384)
#define O_WGT    (O_TOK + 16384)
#define O_SLOTNK (O_WGT + 16384)
#define O_XG     (O_SLOTNK + 16384)                 // bf16 [4096][2048] = 16.78 MB
#define O_HBUF   (O_XG + (size_t)NSLOT*DMODEL*2)    // bf16 [4096][3584] = 29.36 MB
// ypart aliases xg: xg dead after k_upgate, ypart born in k_down.

__device__ __forceinline__ unsigned short f2b_rne(float f) {
  unsigned u = __builtin_bit_cast(unsigned, f);
  u += 0x7FFFu + ((u >> 16) & 1u);
  return (unsigned short)(u >> 16);
}
__device__ __forceinline__ float b2f(unsigned short h) {
  unsigned u = ((unsigned)h) << 16;
  return __builtin_bit_cast(float, u);
}
__device__ __forceinline__ unsigned pk2(float lo, float hi) {
  unsigned r;
  asm("v_cvt_pk_bf16_f32 %0, %1, %2" : "=v"(r) : "v"(lo), "v"(hi));
  return r;
}
__device__ __forceinline__ bf16x8 pack8(float4 a, float4 b) {
  union { unsigned u[4]; bf16x8 v; } r;
  r.u[0] = pk2(a.x, a.y); r.u[1] = pk2(a.z, a.w);
  r.u[2] = pk2(b.x, b.y); r.u[3] = pk2(b.z, b.w);
  return r.v;
}

// ---------------- K0: zero counters ----------------
__global__ void k_zero(int* counts, int* cursor) {
  int t = threadIdx.x;
  if (t < EXP) { counts[t] = 0; cursor[t] = 0; }
}

// ---------------- K1: router (fp32, exact top-4 like lax.top_k) ----------------
__global__ void k_gate(const float* __restrict__ x, const float* __restrict__ gi,
                       int* __restrict__ topi, float* __restrict__ topw,
                       int* __restrict__ counts) {
  int n = blockIdx.x;
  int lane = threadIdx.x & 63, wave = threadIdx.x >> 6;
  __shared__ float lg[EXP];
  const float4* xr = (const float4*)(x + (size_t)n * DMODEL);
  #pragma unroll
  for (int i = 0; i < 4; ++i) {
    int e = wave * 4 + i;
    const float4* gr = (const float4*)(gi + (size_t)e * DMODEL);
    float s = 0.f;
    #pragma unroll
    for (int j = 0; j < 8; ++j) {
      float4 a = xr[j*64 + lane];
      float4 b = gr[j*64 + lane];
      s += a.x*b.x + a.y*b.y + a.z*b.z + a.w*b.w;
    }
    #pragma unroll
    for (int off = 32; off; off >>= 1) s += __shfl_xor(s, off);
    if (lane == 0) lg[e] = s;
  }
  __syncthreads();
  if (threadIdx.x == 0) {
    float v[EXP];
    #pragma unroll
    for (int j = 0; j < EXP; ++j) v[j] = lg[j];
    int bi[TOPK]; float bv[TOPK];
    #pragma unroll
    for (int k = 0; k < TOPK; ++k) {
      float best = -3.4e38f; int bidx = 0;
      for (int j = 0; j < EXP; ++j) if (v[j] > best) { best = v[j]; bidx = j; }
      bv[k] = best; bi[k] = bidx; v[bidx] = -3.4e38f;
    }
    float m = bv[0], ss = 0.f, w[TOPK];
    #pragma unroll
    for (int k = 0; k < TOPK; ++k) { w[k] = expf(bv[k] - m); ss += w[k]; }
    #pragma unroll
    for (int k = 0; k < TOPK; ++k) {
      topi[n*TOPK + k] = bi[k];
      topw[n*TOPK + k] = w[k] / ss;
      atomicAdd(&counts[bi[k]], 1);
    }
  }
}

// ---------------- K2: prefix + 64-row chunk table ----------------
__global__ void k_prefix(const int* __restrict__ counts, int* __restrict__ basep,
                         int* __restrict__ chtab) {
  if (threadIdx.x == 0) {
    int acc = 0;
    for (int e = 0; e < EXP; ++e) { basep[e] = acc; acc += counts[e]; }
    int c = 0;
    for (int e = 0; e < EXP; ++e) {
      int nm = (counts[e] + MCH - 1) / MCH;
      for (int m = 0; m < nm; ++m) { chtab[1 + c] = (e << 8) | m; ++c; }
    }
    chtab[0] = c;
    for (; c < NCHMAX; ++c) chtab[1 + c] = -1;
  }
}

// ---------------- K3: scatter assignments into expert-sorted slots ----------------
__global__ void k_scatter(const int* __restrict__ topi, const float* __restrict__ topw,
                          const int* __restrict__ basep, int* __restrict__ cursor,
                          int* __restrict__ tok, float* __restrict__ wgt,
                          int* __restrict__ slotnk) {
  int n = blockIdx.x * blockDim.x + threadIdx.x;
  if (n >= NTOK) return;
  #pragma unroll
  for (int k = 0; k < TOPK; ++k) {
    int e = topi[n*TOPK + k];
    int pos = atomicAdd(&cursor[e], 1);
    int slot = basep[e] + pos;
    tok[slot] = n;
    wgt[slot] = topw[n*TOPK + k];
    slotnk[n*TOPK + k] = slot;
  }
}

// ---------------- K3b: gather x rows into expert-sorted bf16 buffer ----------------
__global__ void k_gather(const float* __restrict__ x, const int* __restrict__ tok,
                         unsigned short* __restrict__ xg) {
  int slot = blockIdx.x;
  int t = tok[slot];
  int c0 = threadIdx.x * 8;
  const float* src = x + (size_t)t * DMODEL + c0;
  float4 a = *(const float4*)(src);
  float4 b = *(const float4*)(src + 4);
  uint4 o = {pk2(a.x, a.y), pk2(a.z, a.w), pk2(b.x, b.y), pk2(b.z, b.w)};
  *(uint4*)(xg + (size_t)slot * DMODEL + c0) = o;
}

// ---------------- K4: fused up+gate — barrier-free, all-register streaming -------
// Block = 4 independent waves. Wave w: H rows [ht*64 + w*16, +16) x 64 M rows.
// A-fragments (x rows) loaded DIRECT from global xg (same lane pattern as B:
// row=lane&15, k=(lane>>4)*8) — L1/L2-served, no LDS, no barriers anywhere.
// Register double-buffer: prefetch step k+1 (A frags + raw W) during MFMA(k).
#define UG_STEP(AC, AN, PUC, PGC, PUN, PGN, KN) do {                           \
    int o_ = (KN) * 32;                                                        \
    AN[0] = *(const bf16x8*)(ax[0] + o_);                                      \
    AN[1] = *(const bf16x8*)(ax[1] + o_);                                      \
    AN[2] = *(const bf16x8*)(ax[2] + o_);                                      \
    AN[3] = *(const bf16x8*)(ax[3] + o_);                                      \
    float4 u0_ = *(const float4*)(wu + o_);                                    \
    float4 u1_ = *(const float4*)(wu + o_ + 4);                                \
    float4 g0_ = *(const float4*)(wg + o_);                                    \
    float4 g1_ = *(const float4*)(wg + o_ + 4);                                \
    _Pragma("unroll")                                                          \
    for (int t_ = 0; t_ < 4; ++t_) {                                           \
      ua[t_] = __builtin_amdgcn_mfma_f32_16x16x32_bf16(AC[t_], PUC, ua[t_], 0, 0, 0); \
      ga[t_] = __builtin_amdgcn_mfma_f32_16x16x32_bf16(AC[t_], PGC, ga[t_], 0, 0, 0); \
    }                                                                          \
    PUN = pack8(u0_, u1_);                                                     \
    PGN = pack8(g0_, g1_);                                                     \
  } while (0)

__global__ __launch_bounds__(256, 3) void k_upgate(
    const unsigned short* __restrict__ xg,
    const float* __restrict__ Wu, const float* __restrict__ Wg,
    const int* __restrict__ counts, const int* __restrict__ basep,
    const int* __restrict__ chtab, const float* __restrict__ wgt,
    unsigned short* __restrict__ hbuf) {
  int bid = blockIdx.x;
  // XCD swizzle: consecutive lb land on the same XCD. cid-minor decode:
  // adjacent lb = same ht, sibling m-chunks (same expert) -> share weight rows in L2.
  int lb  = (bid & 7) * (NCHMAX*HT_TILES/8) + (bid >> 3);
  int ht  = lb / NCHMAX, cid = lb % NCHMAX;
  int ent = chtab[1 + cid];
  if (ent < 0) return;
  int e = ent >> 8, mch = ent & 255;
  int n_e = counts[e], base_e = basep[e], mstart = mch * MCH;

  int tid = threadIdx.x;
  int lane = tid & 63, wave = tid >> 6;
  int col  = lane & 15;          // fragment row index (M for A, H for B)
  int krow = lane >> 4;          // k sub-block 0..3 (k = krow*8 .. +8)

  // per-lane A bases (4 m-tiles), direct global
  const unsigned short* ax[4];
  #pragma unroll
  for (int t = 0; t < 4; ++t) {
    int slotr = base_e + mstart + t*16 + col;
    if (slotr > NSLOT-1) slotr = NSLOT-1;
    ax[t] = xg + (size_t)slotr*DMODEL + krow*8;
  }
  const float* wu = Wu + ((size_t)e*DFFN + (size_t)(ht*64 + wave*16 + col))*DMODEL + krow*8;
  const float* wg = Wg + ((size_t)e*DFFN + (size_t)(ht*64 + wave*16 + col))*DMODEL + krow*8;

  // prologue: step 0 fragments
  bf16x8 a0[4], a1[4], pu0, pg0, pu1, pg1;
  {
    a0[0] = *(const bf16x8*)(ax[0]);
    a0[1] = *(const bf16x8*)(ax[1]);
    a0[2] = *(const bf16x8*)(ax[2]);
    a0[3] = *(const bf16x8*)(ax[3]);
    float4 u0 = *(const float4*)(wu);
    float4 u1 = *(const float4*)(wu + 4);
    float4 g0 = *(const float4*)(wg);
    float4 g1 = *(const float4*)(wg + 4);
    pu0 = pack8(u0, u1); pg0 = pack8(g0, g1);
  }

  f32x4 ua[4], ga[4];
  #pragma unroll
  for (int t = 0; t < 4; ++t) { f32x4 z = {0.f,0.f,0.f,0.f}; ua[t] = z; ga[t] = z; }

  // 64 k-steps of 32; ping-pong register buffers; no barriers.
  #pragma unroll 1
  for (int kc = 0; kc < DMODEL/32; kc += 2) {
    UG_STEP(a0, a1, pu0, pg0, pu1, pg1, kc + 1);
    int kn2 = kc + 2; if (kn2 > DMODEL/32 - 1) kn2 = DMODEL/32 - 1;
    UG_STEP(a1, a0, pu1, pg1, pu0, pg0, kn2);
  }

  // epilogue: h = silu(g)*u * gate_weight -> bf16 hbuf
  #pragma unroll
  for (int t = 0; t < 4; ++t)
    #pragma unroll
    for (int r = 0; r < 4; ++r) {
      int ml = t*16 + krow*4 + r;
      if (mstart + ml < n_e) {
        float w = wgt[base_e + mstart + ml];
        float u = ua[t][r], g = ga[t][r];
        float hv = u * (g / (1.f + expf(-g))) * w;
        int slot = base_e + mstart + ml;
        hbuf[(size_t)slot*DFFN + ht*64 + wave*16 + col] = f2b_rne(hv);
      }
    }
}

// ---------------- K5: down-proj — barrier-free, all-register streaming ----------
#define DN_STEP(AC, AN, PDC, PDN, KN) do {                                     \
    int o_ = (KN) * 32;                                                        \
    AN[0] = *(const bf16x8*)(ah[0] + o_);                                      \
    AN[1] = *(const bf16x8*)(ah[1] + o_);                                      \
    AN[2] = *(const bf16x8*)(ah[2] + o_);                                      \
    AN[3] = *(const bf16x8*)(ah[3] + o_);                                      \
    float4 d0_ = *(const float4*)(wd + o_);                                    \
    float4 d1_ = *(const float4*)(wd + o_ + 4);                                \
    _Pragma("unroll")                                                          \
    for (int t_ = 0; t_ < 4; ++t_)                                             \
      acc[t_] = __builtin_amdgcn_mfma_f32_16x16x32_bf16(AC[t_], PDC, acc[t_], 0, 0, 0); \
    PDN = pack8(d0_, d1_);                                                     \
  } while (0)

__global__ __launch_bounds__(256, 3) void k_down(
    const unsigned short* __restrict__ hbuf, const float* __restrict__ Wd,
    const int* __restrict__ counts, const int* __restrict__ basep,
    const int* __restrict__ chtab,
    unsigned short* __restrict__ ypart) {
  int bid = blockIdx.x;
  int lb  = (bid & 7) * (NCHMAX*CT_TILES/8) + (bid >> 3);
  int ct  = lb / NCHMAX, cid = lb % NCHMAX;
  int ent = chtab[1 + cid];
  if (ent < 0) return;
  int e = ent >> 8, mch = ent & 255;
  int n_e = counts[e], base_e = basep[e], mstart = mch * MCH;

  int tid = threadIdx.x;
  int lane = tid & 63, wave = tid >> 6;
  int col  = lane & 15;
  int krow = lane >> 4;

  const unsigned short* ah[4];
  #pragma unroll
  for (int t = 0; t < 4; ++t) {
    int slotr = base_e + mstart + t*16 + col;
    if (slotr > NSLOT-1) slotr = NSLOT-1;
    ah[t] = hbuf + (size_t)slotr*DFFN + krow*8;
  }
  const float* wd = Wd + ((size_t)e*DMODEL + (size_t)(ct*64 + wave*16 + col))*DFFN + krow*8;

  bf16x8 a0[4], a1[4], pd0, pd1;
  {
    a0[0] = *(const bf16x8*)(ah[0]);
    a0[1] = *(const bf16x8*)(ah[1]);
    a0[2] = *(const bf16x8*)(ah[2]);
    a0[3] = *(const bf16x8*)(ah[3]);
    float4 d0 = *(const float4*)(wd);
    float4 d1 = *(const float4*)(wd + 4);
    pd0 = pack8(d0, d1);
  }

  f32x4 acc[4];
  #pragma unroll
  for (int t = 0; t < 4; ++t) { f32x4 z = {0.f,0.f,0.f,0.f}; acc[t] = z; }

  // 112 k-steps of 32
  #pragma unroll 1
  for (int hc = 0; hc < DFFN/32; hc += 2) {
    DN_STEP(a0, a1, pd0, pd1, hc + 1);
    int kn2 = hc + 2; if (kn2 > DFFN/32 - 1) kn2 = DFFN/32 - 1;
    DN_STEP(a1, a0, pd1, pd0, kn2);
  }

  #pragma unroll
  for (int t = 0; t < 4; ++t)
    #pragma unroll
    for (int r = 0; r < 4; ++r) {
      int ml = t*16 + krow*4 + r;
      if (mstart + ml < n_e) {
        int slot = base_e + mstart + ml;
        ypart[(size_t)slot*DMODEL + ct*64 + wave*16 + col] = f2b_rne(acc[t][r]);
      }
    }
}

// ---------------- K6: combine 4 expert partials per token -> fp32 out ----------------
__global__ void k_combine(const unsigned short* __restrict__ ypart,
                          const int* __restrict__ slotnk, float* __restrict__ out) {
  int n = blockIdx.x, tid = threadIdx.x;
  int c0 = tid * 8;
  float acc[8] = {0.f,0.f,0.f,0.f,0.f,0.f,0.f,0.f};
  #pragma unroll
  for (int k = 0; k < TOPK; ++k) {
    int slot = slotnk[n*TOPK + k];
    uint4 v = *(const uint4*)(ypart + (size_t)slot*DMODEL + c0);
    const unsigned short* p = (const unsigned short*)&v;
    #pragma unroll
    for (int j = 0; j < 8; ++j) acc[j] += b2f(p[j]);
  }
  float4 o0 = {acc[0], acc[1], acc[2], acc[3]};
  float4 o1 = {acc[4], acc[5], acc[6], acc[7]};
  *(float4*)(out + (size_t)n*DMODEL + c0)     = o0;
  *(float4*)(out + (size_t)n*DMODEL + c0 + 4) = o1;
}

// ---------------- launcher ----------------
extern "C" void kernel_launch(void* const* d_in, const int* in_sizes, int n_in,
                              void* d_out, int out_size, void* d_ws, size_t ws_size,
                              hipStream_t stream) {
  const float* x     = (const float*)d_in[0];
  const float* W_up  = (const float*)d_in[1];
  const float* W_gt  = (const float*)d_in[2];
  const float* W_dn  = (const float*)d_in[3];
  const float* g_in  = (const float*)d_in[4];
  float* out = (float*)d_out;
  char* ws = (char*)d_ws;

  int*   counts = (int*)(ws + O_COUNTS);
  int*   basep  = (int*)(ws + O_BASE);
  int*   cursor = (int*)(ws + O_CURSOR);
  int*   chtab  = (int*)(ws + O_CHT);
  int*   topi   = (int*)(ws + O_TOPI);
  float* topw   = (float*)(ws + O_TOPW);
  int*   tok    = (int*)(ws + O_TOK);
  float* wgt    = (float*)(ws + O_WGT);
  int*   slotnk = (int*)(ws + O_SLOTNK);
  unsigned short* xg    = (unsigned short*)(ws + O_XG);
  unsigned short* hbuf  = (unsigned short*)(ws + O_HBUF);
  unsigned short* ypart = xg;   // alias: xg dead after k_upgate

  k_zero   <<<1, 64, 0, stream>>>(counts, cursor);
  k_gate   <<<NTOK, 256, 0, stream>>>(x, g_in, topi, topw, counts);
  k_prefix <<<1, 64, 0, stream>>>(counts, basep, chtab);
  k_scatter<<<4, 256, 0, stream>>>(topi, topw, basep, cursor, tok, wgt, slotnk);
  k_gather <<<NSLOT, 256, 0, stream>>>(x, tok, xg);
  k_upgate <<<NCHMAX*HT_TILES, 256, 0, stream>>>(xg, W_up, W_gt, counts, basep, chtab, wgt, hbuf);
  k_down   <<<NCHMAX*CT_TILES, 256, 0, stream>>>(hbuf, W_dn, counts, basep, chtab, ypart);
  k_combine<<<NTOK, 256, 0, stream>>>(ypart, slotnk, out);
}

// Round 11
// 998.365 us; speedup vs baseline: 1.7414x; 1.7414x over previous
//
#include <hip/hip_runtime.h>
#include <math.h>

// ---------------- problem constants ----------------
#define NTOK   1024      // B*T
#define EXP    16
#define TOPK   4
#define DMODEL 2048
#define DFFN   3584
#define HT_TILES 56      // DFFN/64  (64 H per block)
#define CT_TILES 32      // DMODEL/64 (64 C per block)
#define NSLOT  4096      // NTOK*TOPK, always exactly filled
#define MCH    128       // M-chunk rows
#define NCHMAX 48        // max sum of ceil(n_e/128) = 47, padded

typedef __attribute__((ext_vector_type(8))) short bf16x8;
typedef __attribute__((ext_vector_type(4))) float f32x4;

// ---------------- workspace layout (bytes) ----------------
#define O_COUNTS 0
#define O_BASE   256
#define O_CURSOR 512
#define O_CHT    1024                               // int[1+NCHMAX] chunk table
#define O_TOPI   4096
#define O_TOPW   (O_TOPI + 16384)
#define O_TOK    (O_TOPW + 16384)
#define O_WGT    (O_TOK + 16384)
#define O_SLOTNK (O_WGT + 16384)
#define O_XG     (O_SLOTNK + 16384)                 // bf16 [4096][2048] = 16.78 MB
#define O_HBUF   (O_XG + (size_t)NSLOT*DMODEL*2)    // bf16 [4096][3584] = 29.36 MB
// ypart aliases xg: xg dead after k_upgate, ypart born in k_down.

#define VMW(N) asm volatile("s_waitcnt vmcnt(" #N ")" ::: "memory")
#define LKW0() asm volatile("s_waitcnt lgkmcnt(0)" ::: "memory")
#define BAR()  __builtin_amdgcn_s_barrier()
#define SBAR() __builtin_amdgcn_sched_barrier(0)

__device__ __forceinline__ unsigned short f2b_rne(float f) {
  unsigned u = __builtin_bit_cast(unsigned, f);
  u += 0x7FFFu + ((u >> 16) & 1u);
  return (unsigned short)(u >> 16);
}
__device__ __forceinline__ float b2f(unsigned short h) {
  unsigned u = ((unsigned)h) << 16;
  return __builtin_bit_cast(float, u);
}
__device__ __forceinline__ unsigned pk2(float lo, float hi) {
  unsigned r;
  asm("v_cvt_pk_bf16_f32 %0, %1, %2" : "=v"(r) : "v"(lo), "v"(hi));
  return r;
}
__device__ __forceinline__ bf16x8 pack8(float4 a, float4 b) {
  union { unsigned u[4]; bf16x8 v; } r;
  r.u[0] = pk2(a.x, a.y); r.u[1] = pk2(a.z, a.w);
  r.u[2] = pk2(b.x, b.y); r.u[3] = pk2(b.z, b.w);
  return r.v;
}

// async 16B global->LDS (wave-uniform LDS base + lane*16; per-lane global src)
__device__ __forceinline__ void gl16(const unsigned short* g, unsigned short* l) {
  __builtin_amdgcn_global_load_lds(
      (const __attribute__((address_space(1))) void*)g,
      (__attribute__((address_space(3))) void*)l, 16, 0, 0);
}

// read one MFMA fragment (8 bf16 = 16B) from swizzled LDS tile (row stride 64)
__device__ __forceinline__ bf16x8 ld_frag(const unsigned short* lds, int row, int chunk) {
  return *(const bf16x8*)(lds + row*64 + ((chunk ^ (row & 7)) * 8));
}

// ---------------- K0: zero counters ----------------
__global__ void k_zero(int* counts, int* cursor) {
  int t = threadIdx.x;
  if (t < EXP) { counts[t] = 0; cursor[t] = 0; }
}

// ---------------- K1: router (fp32, exact top-4 like lax.top_k) ----------------
__global__ void k_gate(const float* __restrict__ x, const float* __restrict__ gi,
                       int* __restrict__ topi, float* __restrict__ topw,
                       int* __restrict__ counts) {
  int n = blockIdx.x;
  int lane = threadIdx.x & 63, wave = threadIdx.x >> 6;
  __shared__ float lg[EXP];
  const float4* xr = (const float4*)(x + (size_t)n * DMODEL);
  #pragma unroll
  for (int i = 0; i < 4; ++i) {
    int e = wave * 4 + i;
    const float4* gr = (const float4*)(gi + (size_t)e * DMODEL);
    float s = 0.f;
    #pragma unroll
    for (int j = 0; j < 8; ++j) {
      float4 a = xr[j*64 + lane];
      float4 b = gr[j*64 + lane];
      s += a.x*b.x + a.y*b.y + a.z*b.z + a.w*b.w;
    }
    #pragma unroll
    for (int off = 32; off; off >>= 1) s += __shfl_xor(s, off);
    if (lane == 0) lg[e] = s;
  }
  __syncthreads();
  if (threadIdx.x == 0) {
    float v[EXP];
    #pragma unroll
    for (int j = 0; j < EXP; ++j) v[j] = lg[j];
    int bi[TOPK]; float bv[TOPK];
    #pragma unroll
    for (int k = 0; k < TOPK; ++k) {
      float best = -3.4e38f; int bidx = 0;
      for (int j = 0; j < EXP; ++j) if (v[j] > best) { best = v[j]; bidx = j; }
      bv[k] = best; bi[k] = bidx; v[bidx] = -3.4e38f;
    }
    float m = bv[0], ss = 0.f, w[TOPK];
    #pragma unroll
    for (int k = 0; k < TOPK; ++k) { w[k] = expf(bv[k] - m); ss += w[k]; }
    #pragma unroll
    for (int k = 0; k < TOPK; ++k) {
      topi[n*TOPK + k] = bi[k];
      topw[n*TOPK + k] = w[k] / ss;
      atomicAdd(&counts[bi[k]], 1);
    }
  }
}

// ---------------- K2: prefix + 128-row chunk table ----------------
__global__ void k_prefix(const int* __restrict__ counts, int* __restrict__ basep,
                         int* __restrict__ chtab) {
  if (threadIdx.x == 0) {
    int acc = 0;
    for (int e = 0; e < EXP; ++e) { basep[e] = acc; acc += counts[e]; }
    int c = 0;
    for (int e = 0; e < EXP; ++e) {
      int nm = (counts[e] + MCH - 1) / MCH;
      for (int m = 0; m < nm; ++m) { chtab[1 + c] = (e << 8) | m; ++c; }
    }
    chtab[0] = c;
    for (; c < NCHMAX; ++c) chtab[1 + c] = -1;
  }
}

// ---------------- K3: scatter assignments into expert-sorted slots ----------------
__global__ void k_scatter(const int* __restrict__ topi, const float* __restrict__ topw,
                          const int* __restrict__ basep, int* __restrict__ cursor,
                          int* __restrict__ tok, float* __restrict__ wgt,
                          int* __restrict__ slotnk) {
  int n = blockIdx.x * blockDim.x + threadIdx.x;
  if (n >= NTOK) return;
  #pragma unroll
  for (int k = 0; k < TOPK; ++k) {
    int e = topi[n*TOPK + k];
    int pos = atomicAdd(&cursor[e], 1);
    int slot = basep[e] + pos;
    tok[slot] = n;
    wgt[slot] = topw[n*TOPK + k];
    slotnk[n*TOPK + k] = slot;
  }
}

// ---------------- K3b: gather x rows into expert-sorted bf16 buffer ----------------
__global__ void k_gather(const float* __restrict__ x, const int* __restrict__ tok,
                         unsigned short* __restrict__ xg) {
  int slot = blockIdx.x;
  int t = tok[slot];
  int c0 = threadIdx.x * 8;
  const float* src = x + (size_t)t * DMODEL + c0;
  float4 a = *(const float4*)(src);
  float4 b = *(const float4*)(src + 4);
  uint4 o = {pk2(a.x, a.y), pk2(a.z, a.w), pk2(b.x, b.y), pk2(b.z, b.w)};
  *(uint4*)(xg + (size_t)slot * DMODEL + c0) = o;
}

// ---------------- K4: fused up+gate (R4 structure + 2-deep W pipeline) ----------
// 4 waves; wave w owns H rows [ht*64 + w*16, +16) x 128 M rows.
// Step kc: BAR; gl16 x(kc+1) [x FIRST: older in vmcnt queue]; issue W(kc+2)->RA;
// VMW(20) [retires x(kc) only]; BAR; MFMA(kc) with PK=pack(W(kc));
// VMW(12) [retires W(kc+1)=RB]; pack RB -> PKN.
#define UG_STEP(XSC, XSN, RA, RB, PK, PKN, KC) do {                            \
    BAR();                                                                     \
    int kx_ = (KC) + 1; if (kx_ > DMODEL/64 - 1) kx_ = DMODEL/64 - 1;          \
    _Pragma("unroll")                                                          \
    for (int i_ = 0; i_ < 4; ++i_)                                             \
      gl16(bx[i_] + kx_*64, (XSN) + (i_*4 + wave)*8*64);                       \
    SBAR();                                                                    \
    int kn_ = (KC) + 2; if (kn_ > DMODEL/64 - 1) kn_ = DMODEL/64 - 1;          \
    const float* pu_ = wu_row + kn_*64;                                        \
    const float* pg_ = wg_row + kn_*64;                                        \
    RA[0] = *(const float4*)(pu_);      RA[1] = *(const float4*)(pu_ + 4);     \
    RA[2] = *(const float4*)(pu_ + 32); RA[3] = *(const float4*)(pu_ + 36);    \
    RA[4] = *(const float4*)(pg_);      RA[5] = *(const float4*)(pg_ + 4);     \
    RA[6] = *(const float4*)(pg_ + 32); RA[7] = *(const float4*)(pg_ + 36);    \
    SBAR();                                                                    \
    VMW(20);                                                                   \
    BAR();                                                                     \
    __builtin_amdgcn_s_setprio(1);                                             \
    _Pragma("unroll")                                                          \
    for (int kk_ = 0; kk_ < 2; ++kk_) {                                        \
      int chunk_ = kk_*4 + (lane >> 4);                                        \
      _Pragma("unroll")                                                        \
      for (int t_ = 0; t_ < 8; ++t_) {                                         \
        bf16x8 a_ = ld_frag((XSC), t_*16 + col, chunk_);                       \
        ua[t_] = __builtin_amdgcn_mfma_f32_16x16x32_bf16(a_, PK[kk_],   ua[t_], 0, 0, 0); \
        ga[t_] = __builtin_amdgcn_mfma_f32_16x16x32_bf16(a_, PK[2+kk_], ga[t_], 0, 0, 0); \
      }                                                                        \
    }                                                                          \
    __builtin_amdgcn_s_setprio(0);                                             \
    VMW(12);                                                                   \
    PKN[0] = pack8(RB[0], RB[1]); PKN[1] = pack8(RB[2], RB[3]);                \
    PKN[2] = pack8(RB[4], RB[5]); PKN[3] = pack8(RB[6], RB[7]);                \
  } while (0)

__global__ __launch_bounds__(256, 3) void k_upgate(
    const unsigned short* __restrict__ xg,
    const float* __restrict__ Wu, const float* __restrict__ Wg,
    const int* __restrict__ counts, const int* __restrict__ basep,
    const int* __restrict__ chtab, const float* __restrict__ wgt,
    unsigned short* __restrict__ hbuf) {
  int bid = blockIdx.x;
  // XCD-bijective swizzle; cid-minor decode: adjacent blocks on an XCD share
  // ht AND (for sibling chunks of one expert) the same weight panel -> L2 hit.
  int lb  = (bid & 7) * (NCHMAX*HT_TILES/8) + (bid >> 3);
  int cid = lb % NCHMAX, ht = lb / NCHMAX;
  int ent = chtab[1 + cid];
  if (ent < 0) return;
  int e = ent >> 8, mch = ent & 255;
  int n_e = counts[e], base_e = basep[e], mstart = mch * MCH;

  __shared__ unsigned short xs[2][128*64];
  __shared__ float swgt[MCH];

  int tid = threadIdx.x;
  int lane = tid & 63, wave = tid >> 6;
  int col = lane & 15;                 // B row (h) within wave's 16
  int kgrp = (lane >> 4) * 8;
  const float* wu_row = Wu + ((size_t)e * DFFN + (size_t)(ht*64 + wave*16 + col)) * DMODEL + kgrp;
  const float* wg_row = Wg + ((size_t)e * DFFN + (size_t)(ht*64 + wave*16 + col)) * DMODEL + kgrp;

  int xrow_lo = lane >> 3;             // 0..7
  int xpc     = lane & 7;
  int swz     = (xpc ^ xrow_lo) * 8;   // row&7 == xrow_lo

  // per-lane global x source bases for the 4 gl16 issues (8-row groups)
  const unsigned short* bx[4];
  #pragma unroll
  for (int i = 0; i < 4; ++i) {
    int row = (i*4 + wave)*8 + xrow_lo;
    int slotr = base_e + mstart + row;
    if (slotr > NSLOT-1) slotr = NSLOT-1;
    bx[i] = xg + (size_t)slotr*DMODEL + swz;
  }

  if (tid < MCH) {
    int r = mstart + tid;
    swgt[tid] = (r < n_e) ? wgt[base_e + r] : 0.f;
  }
  LKW0();

  // prologue: x(0) [oldest], W(0) -> ra; drain; pack pkA=W(0); issue W(1)->rb
  float4 ra[8], rb[8];
  bf16x8 pkA[4], pkB[4];
  #pragma unroll
  for (int i = 0; i < 4; ++i)
    gl16(bx[i], &xs[0][(i*4 + wave)*8*64]);
  SBAR();
  ra[0] = *(const float4*)(wu_row);      ra[1] = *(const float4*)(wu_row + 4);
  ra[2] = *(const float4*)(wu_row + 32); ra[3] = *(const float4*)(wu_row + 36);
  ra[4] = *(const float4*)(wg_row);      ra[5] = *(const float4*)(wg_row + 4);
  ra[6] = *(const float4*)(wg_row + 32); ra[7] = *(const float4*)(wg_row + 36);
  SBAR();
  VMW(0);   // prologue-only full drain: x(0) + W(0) complete
  pkA[0] = pack8(ra[0], ra[1]); pkA[1] = pack8(ra[2], ra[3]);
  pkA[2] = pack8(ra[4], ra[5]); pkA[3] = pack8(ra[6], ra[7]);
  rb[0] = *(const float4*)(wu_row + 64); rb[1] = *(const float4*)(wu_row + 68);
  rb[2] = *(const float4*)(wu_row + 96); rb[3] = *(const float4*)(wu_row + 100);
  rb[4] = *(const float4*)(wg_row + 64); rb[5] = *(const float4*)(wg_row + 68);
  rb[6] = *(const float4*)(wg_row + 96); rb[7] = *(const float4*)(wg_row + 100);
  SBAR();

  f32x4 ua[8], ga[8];
  #pragma unroll
  for (int t = 0; t < 8; ++t) { f32x4 z = {0.f,0.f,0.f,0.f}; ua[t] = z; ga[t] = z; }

  #pragma unroll 1
  for (int kc = 0; kc < DMODEL/64; kc += 2) {
    UG_STEP(xs[0], xs[1], ra, rb, pkA, pkB, kc);
    UG_STEP(xs[1], xs[0], rb, ra, pkB, pkA, kc + 1);
  }

  // epilogue: h = silu(g)*u * gate_weight -> bf16 hbuf
  #pragma unroll
  for (int t = 0; t < 8; ++t)
    #pragma unroll
    for (int r = 0; r < 4; ++r) {
      int ml = t*16 + (lane >> 4)*4 + r;
      if (mstart + ml < n_e) {
        float u = ua[t][r], g = ga[t][r];
        float hv = u * (g / (1.f + expf(-g))) * swgt[ml];
        int slot = base_e + mstart + ml;
        hbuf[(size_t)slot*DFFN + ht*64 + wave*16 + col] = f2b_rne(hv);
      }
    }
}

// ---------------- K5: down-proj (R4 structure + 2-deep W pipeline) --------------
#define DN_STEP(XSC, XSN, RA, RB, PK, PKN, KC) do {                            \
    BAR();                                                                     \
    int kx_ = (KC) + 1; if (kx_ > DFFN/64 - 1) kx_ = DFFN/64 - 1;              \
    _Pragma("unroll")                                                          \
    for (int i_ = 0; i_ < 4; ++i_)                                             \
      gl16(bh[i_] + kx_*64, (XSN) + (i_*4 + wave)*8*64);                       \
    SBAR();                                                                    \
    int kn_ = (KC) + 2; if (kn_ > DFFN/64 - 1) kn_ = DFFN/64 - 1;              \
    const float* pd_ = wd_row + kn_*64;                                        \
    RA[0] = *(const float4*)(pd_);      RA[1] = *(const float4*)(pd_ + 4);     \
    RA[2] = *(const float4*)(pd_ + 32); RA[3] = *(const float4*)(pd_ + 36);    \
    SBAR();                                                                    \
    VMW(12);                                                                   \
    BAR();                                                                     \
    __builtin_amdgcn_s_setprio(1);                                             \
    _Pragma("unroll")                                                          \
    for (int kk_ = 0; kk_ < 2; ++kk_) {                                        \
      int chunk_ = kk_*4 + (lane >> 4);                                        \
      _Pragma("unroll")                                                        \
      for (int t_ = 0; t_ < 8; ++t_) {                                         \
        bf16x8 a_ = ld_frag((XSC), t_*16 + col, chunk_);                       \
        acc[t_] = __builtin_amdgcn_mfma_f32_16x16x32_bf16(a_, PK[kk_], acc[t_], 0, 0, 0); \
      }                                                                        \
    }                                                                          \
    __builtin_amdgcn_s_setprio(0);                                             \
    VMW(8);                                                                    \
    PKN[0] = pack8(RB[0], RB[1]); PKN[1] = pack8(RB[2], RB[3]);                \
  } while (0)

__global__ __launch_bounds__(256, 3) void k_down(
    const unsigned short* __restrict__ hbuf, const float* __restrict__ Wd,
    const int* __restrict__ counts, const int* __restrict__ basep,
    const int* __restrict__ chtab,
    unsigned short* __restrict__ ypart) {
  int bid = blockIdx.x;
  int lb  = (bid & 7) * (NCHMAX*CT_TILES/8) + (bid >> 3);
  int cid = lb % NCHMAX, ct = lb / NCHMAX;
  int ent = chtab[1 + cid];
  if (ent < 0) return;
  int e = ent >> 8, mch = ent & 255;
  int n_e = counts[e], base_e = basep[e], mstart = mch * MCH;

  __shared__ unsigned short hs[2][128*64];

  int tid = threadIdx.x;
  int lane = tid & 63, wave = tid >> 6;
  int col = lane & 15;
  int kgrp = (lane >> 4) * 8;
  const float* wd_row = Wd + ((size_t)e * DMODEL + (size_t)(ct*64 + wave*16 + col)) * DFFN + kgrp;

  int xrow_lo = lane >> 3;
  int xpc     = lane & 7;
  int swz     = (xpc ^ xrow_lo) * 8;

  const unsigned short* bh[4];
  #pragma unroll
  for (int i = 0; i < 4; ++i) {
    int row = (i*4 + wave)*8 + xrow_lo;
    int slotr = base_e + mstart + row;
    if (slotr > NSLOT-1) slotr = NSLOT-1;
    bh[i] = hbuf + (size_t)slotr*DFFN + swz;
  }

  // prologue: h(0) [oldest], W(0)->ra; drain; pack pkA; issue W(1)->rb
  float4 ra[4], rb[4];
  bf16x8 pkA[2], pkB[2];
  #pragma unroll
  for (int i = 0; i < 4; ++i)
    gl16(bh[i], &hs[0][(i*4 + wave)*8*64]);
  SBAR();
  ra[0] = *(const float4*)(wd_row);      ra[1] = *(const float4*)(wd_row + 4);
  ra[2] = *(const float4*)(wd_row + 32); ra[3] = *(const float4*)(wd_row + 36);
  SBAR();
  VMW(0);
  pkA[0] = pack8(ra[0], ra[1]); pkA[1] = pack8(ra[2], ra[3]);
  rb[0] = *(const float4*)(wd_row + 64); rb[1] = *(const float4*)(wd_row + 68);
  rb[2] = *(const float4*)(wd_row + 96); rb[3] = *(const float4*)(wd_row + 100);
  SBAR();

  f32x4 acc[8];
  #pragma unroll
  for (int t = 0; t < 8; ++t) { f32x4 z = {0.f,0.f,0.f,0.f}; acc[t] = z; }

  #pragma unroll 1
  for (int hc = 0; hc < DFFN/64; hc += 2) {
    DN_STEP(hs[0], hs[1], ra, rb, pkA, pkB, hc);
    DN_STEP(hs[1], hs[0], rb, ra, pkB, pkA, hc + 1);
  }

  #pragma unroll
  for (int t = 0; t < 8; ++t)
    #pragma unroll
    for (int r = 0; r < 4; ++r) {
      int ml = t*16 + (lane >> 4)*4 + r;
      if (mstart + ml < n_e) {
        int slot = base_e + mstart + ml;
        ypart[(size_t)slot*DMODEL + ct*64 + wave*16 + col] = f2b_rne(acc[t][r]);
      }
    }
}

// ---------------- K6: combine 4 expert partials per token -> fp32 out ----------------
__global__ void k_combine(const unsigned short* __restrict__ ypart,
                          const int* __restrict__ slotnk, float* __restrict__ out) {
  int n = blockIdx.x, tid = threadIdx.x;
  int c0 = tid * 8;
  float acc[8] = {0.f,0.f,0.f,0.f,0.f,0.f,0.f,0.f};
  #pragma unroll
  for (int k = 0; k < TOPK; ++k) {
    int slot = slotnk[n*TOPK + k];
    uint4 v = *(const uint4*)(ypart + (size_t)slot*DMODEL + c0);
    const unsigned short* p = (const unsigned short*)&v;
    #pragma unroll
    for (int j = 0; j < 8; ++j) acc[j] += b2f(p[j]);
  }
  float4 o0 = {acc[0], acc[1], acc[2], acc[3]};
  float4 o1 = {acc[4], acc[5], acc[6], acc[7]};
  *(float4*)(out + (size_t)n*DMODEL + c0)     = o0;
  *(float4*)(out + (size_t)n*DMODEL + c0 + 4) = o1;
}

// ---------------- launcher ----------------
extern "C" void kernel_launch(void* const* d_in, const int* in_sizes, int n_in,
                              void* d_out, int out_size, void* d_ws, size_t ws_size,
                              hipStream_t stream) {
  const float* x     = (const float*)d_in[0];
  const float* W_up  = (const float*)d_in[1];
  const float* W_gt  = (const float*)d_in[2];
  const float* W_dn  = (const float*)d_in[3];
  const float* g_in  = (const float*)d_in[4];
  float* out = (float*)d_out;
  char* ws = (char*)d_ws;

  int*   counts = (int*)(ws + O_COUNTS);
  int*   basep  = (int*)(ws + O_BASE);
  int*   cursor = (int*)(ws + O_CURSOR);
  int*   chtab  = (int*)(ws + O_CHT);
  int*   topi   = (int*)(ws + O_TOPI);
  float* topw   = (float*)(ws + O_TOPW);
  int*   tok    = (int*)(ws + O_TOK);
  float* wgt    = (float*)(ws + O_WGT);
  int*   slotnk = (int*)(ws + O_SLOTNK);
  unsigned short* xg    = (unsigned short*)(ws + O_XG);
  unsigned short* hbuf  = (unsigned short*)(ws + O_HBUF);
  unsigned short* ypart = xg;   // alias: xg dead after k_upgate

  k_zero   <<<1, 64, 0, stream>>>(counts, cursor);
  k_gate   <<<NTOK, 256, 0, stream>>>(x, g_in, topi, topw, counts);
  k_prefix <<<1, 64, 0, stream>>>(counts, basep, chtab);
  k_scatter<<<4, 256, 0, stream>>>(topi, topw, basep, cursor, tok, wgt, slotnk);
  k_gather <<<NSLOT, 256, 0, stream>>>(x, tok, xg);
  k_upgate <<<NCHMAX*HT_TILES, 256, 0, stream>>>(xg, W_up, W_gt, counts, basep, chtab, wgt, hbuf);
  k_down   <<<NCHMAX*CT_TILES, 256, 0, stream>>>(hbuf, W_dn, counts, basep, chtab, ypart);
  k_combine<<<NTOK, 256, 0, stream>>>(ypart, slotnk, out);
}

// Round 12
// 793.722 us; speedup vs baseline: 2.1904x; 1.2578x over previous
//
#include <hip/hip_runtime.h>
#include <math.h>

// ---------------- problem constants ----------------
#define NTOK   1024      // B*T
#define EXP    16
#define TOPK   4
#define DMODEL 2048
#define DFFN   3584
#define HT_TILES 56      // DFFN/64  (64 H per block)
#define CT_TILES 32      // DMODEL/64 (64 C per block)
#define NSLOT  4096      // NTOK*TOPK, always exactly filled
#define MCH    256       // M-chunk rows (V-minimizing: weights re-read per chunk)
#define NCHMAX 32        // max sum of ceil(n_e/256) = 31, padded

typedef __attribute__((ext_vector_type(8))) short bf16x8;
typedef __attribute__((ext_vector_type(4))) float f32x4;

// ---------------- workspace layout (bytes) ----------------
#define O_COUNTS 0
#define O_BASE   256
#define O_CURSOR 512
#define O_CHT    1024                               // int[1+NCHMAX] chunk table
#define O_TOPI   4096
#define O_TOPW   (O_TOPI + 16384)
#define O_TOK    (O_TOPW + 16384)
#define O_WGT    (O_TOK + 16384)
#define O_SLOTNK (O_WGT + 16384)
#define O_XG     (O_SLOTNK + 16384)                 // bf16 [4096][2048] = 16.78 MB
#define O_HBUF   (O_XG + (size_t)NSLOT*DMODEL*2)    // bf16 [4096][3584] = 29.36 MB
// ypart aliases xg: xg dead after k_upgate, ypart born in k_down.

#define VMW(N) asm volatile("s_waitcnt vmcnt(" #N ")" ::: "memory")
#define LKW0() asm volatile("s_waitcnt lgkmcnt(0)" ::: "memory")
#define BAR()  __builtin_amdgcn_s_barrier()

__device__ __forceinline__ unsigned short f2b_rne(float f) {
  unsigned u = __builtin_bit_cast(unsigned, f);
  u += 0x7FFFu + ((u >> 16) & 1u);
  return (unsigned short)(u >> 16);
}
__device__ __forceinline__ float b2f(unsigned short h) {
  unsigned u = ((unsigned)h) << 16;
  return __builtin_bit_cast(float, u);
}
__device__ __forceinline__ unsigned pk2(float lo, float hi) {
  unsigned r;
  asm("v_cvt_pk_bf16_f32 %0, %1, %2" : "=v"(r) : "v"(lo), "v"(hi));
  return r;
}
__device__ __forceinline__ bf16x8 pack8(float4 a, float4 b) {
  union { unsigned u[4]; bf16x8 v; } r;
  r.u[0] = pk2(a.x, a.y); r.u[1] = pk2(a.z, a.w);
  r.u[2] = pk2(b.x, b.y); r.u[3] = pk2(b.z, b.w);
  return r.v;
}

// async 16B global->LDS (wave-uniform LDS base + lane*16; per-lane global src)
__device__ __forceinline__ void gl16(const unsigned short* g, unsigned short* l) {
  __builtin_amdgcn_global_load_lds(
      (const __attribute__((address_space(1))) void*)g,
      (__attribute__((address_space(3))) void*)l, 16, 0, 0);
}

// read one MFMA fragment (8 bf16 = 16B) from swizzled LDS tile (row stride 64)
__device__ __forceinline__ bf16x8 ld_frag(const unsigned short* lds, int row, int chunk) {
  return *(const bf16x8*)(lds + row*64 + ((chunk ^ (row & 7)) * 8));
}

// ---------------- K0: zero counters ----------------
__global__ void k_zero(int* counts, int* cursor) {
  int t = threadIdx.x;
  if (t < EXP) { counts[t] = 0; cursor[t] = 0; }
}

// ---------------- K1: router (fp32, exact top-4 like lax.top_k) ----------------
__global__ void k_gate(const float* __restrict__ x, const float* __restrict__ gi,
                       int* __restrict__ topi, float* __restrict__ topw,
                       int* __restrict__ counts) {
  int n = blockIdx.x;
  int lane = threadIdx.x & 63, wave = threadIdx.x >> 6;
  __shared__ float lg[EXP];
  const float4* xr = (const float4*)(x + (size_t)n * DMODEL);
  #pragma unroll
  for (int i = 0; i < 4; ++i) {
    int e = wave * 4 + i;
    const float4* gr = (const float4*)(gi + (size_t)e * DMODEL);
    float s = 0.f;
    #pragma unroll
    for (int j = 0; j < 8; ++j) {
      float4 a = xr[j*64 + lane];
      float4 b = gr[j*64 + lane];
      s += a.x*b.x + a.y*b.y + a.z*b.z + a.w*b.w;
    }
    #pragma unroll
    for (int off = 32; off; off >>= 1) s += __shfl_xor(s, off);
    if (lane == 0) lg[e] = s;
  }
  __syncthreads();
  if (threadIdx.x == 0) {
    float v[EXP];
    #pragma unroll
    for (int j = 0; j < EXP; ++j) v[j] = lg[j];
    int bi[TOPK]; float bv[TOPK];
    #pragma unroll
    for (int k = 0; k < TOPK; ++k) {
      float best = -3.4e38f; int bidx = 0;
      for (int j = 0; j < EXP; ++j) if (v[j] > best) { best = v[j]; bidx = j; }
      bv[k] = best; bi[k] = bidx; v[bidx] = -3.4e38f;
    }
    float m = bv[0], ss = 0.f, w[TOPK];
    #pragma unroll
    for (int k = 0; k < TOPK; ++k) { w[k] = expf(bv[k] - m); ss += w[k]; }
    #pragma unroll
    for (int k = 0; k < TOPK; ++k) {
      topi[n*TOPK + k] = bi[k];
      topw[n*TOPK + k] = w[k] / ss;
      atomicAdd(&counts[bi[k]], 1);
    }
  }
}

// ---------------- K2: prefix + 256-row chunk table ----------------
__global__ void k_prefix(const int* __restrict__ counts, int* __restrict__ basep,
                         int* __restrict__ chtab) {
  if (threadIdx.x == 0) {
    int acc = 0;
    for (int e = 0; e < EXP; ++e) { basep[e] = acc; acc += counts[e]; }
    int c = 0;
    for (int e = 0; e < EXP; ++e) {
      int nm = (counts[e] + MCH - 1) / MCH;
      for (int m = 0; m < nm; ++m) { chtab[1 + c] = (e << 8) | m; ++c; }
    }
    chtab[0] = c;
    for (; c < NCHMAX; ++c) chtab[1 + c] = -1;
  }
}

// ---------------- K3: scatter assignments into expert-sorted slots ----------------
__global__ void k_scatter(const int* __restrict__ topi, const float* __restrict__ topw,
                          const int* __restrict__ basep, int* __restrict__ cursor,
                          int* __restrict__ tok, float* __restrict__ wgt,
                          int* __restrict__ slotnk) {
  int n = blockIdx.x * blockDim.x + threadIdx.x;
  if (n >= NTOK) return;
  #pragma unroll
  for (int k = 0; k < TOPK; ++k) {
    int e = topi[n*TOPK + k];
    int pos = atomicAdd(&cursor[e], 1);
    int slot = basep[e] + pos;
    tok[slot] = n;
    wgt[slot] = topw[n*TOPK + k];
    slotnk[n*TOPK + k] = slot;
  }
}

// ---------------- K3b: gather x rows into expert-sorted bf16 buffer ----------------
__global__ void k_gather(const float* __restrict__ x, const int* __restrict__ tok,
                         unsigned short* __restrict__ xg) {
  int slot = blockIdx.x;
  int t = tok[slot];
  int c0 = threadIdx.x * 8;
  const float* src = x + (size_t)t * DMODEL + c0;
  float4 a = *(const float4*)(src);
  float4 b = *(const float4*)(src + 4);
  uint4 o = {pk2(a.x, a.y), pk2(a.z, a.w), pk2(b.x, b.y), pk2(b.z, b.w)};
  *(uint4*)(xg + (size_t)slot * DMODEL + c0) = o;
}

// ---------------- K4: fused up+gate; M=256 chunks (V-minimized), R4 step -------
// 4 waves; wave w owns H rows [ht*64 + w*16, +16) x 256 M rows.
// Step kc: BAR; issue W(kc+1) 8 + gl16 x(kc+1) 8; VMW(16) [x(kc) done];
// BAR; MFMA(kc) [2kk x 16t x 2mats]; VMW(8) [W(kc+1) done]; pack.
#define UG_STEP(XSC, XSN, PC, PN, KC) do {                                     \
    BAR();                                                                     \
    int kn_ = (KC) + 1; if (kn_ > DMODEL/64 - 1) kn_ = DMODEL/64 - 1;          \
    const float* pu_ = wu_row + kn_*64;                                        \
    const float* pg_ = wg_row + kn_*64;                                        \
    float4 r0_ = *(const float4*)(pu_);                                        \
    float4 r1_ = *(const float4*)(pu_ + 4);                                    \
    float4 r2_ = *(const float4*)(pu_ + 32);                                   \
    float4 r3_ = *(const float4*)(pu_ + 36);                                   \
    float4 r4_ = *(const float4*)(pg_);                                        \
    float4 r5_ = *(const float4*)(pg_ + 4);                                    \
    float4 r6_ = *(const float4*)(pg_ + 32);                                   \
    float4 r7_ = *(const float4*)(pg_ + 36);                                   \
    _Pragma("unroll")                                                          \
    for (int i_ = 0; i_ < 8; ++i_)                                             \
      gl16(bx[i_] + kn_*64, (XSN) + (i_*4 + wave)*8*64);                       \
    VMW(16);                                                                   \
    BAR();                                                                     \
    __builtin_amdgcn_s_setprio(1);                                             \
    _Pragma("unroll")                                                          \
    for (int kk_ = 0; kk_ < 2; ++kk_) {                                        \
      int chunk_ = kk_*4 + (lane >> 4);                                        \
      _Pragma("unroll")                                                        \
      for (int t_ = 0; t_ < 16; ++t_) {                                        \
        bf16x8 a_ = ld_frag((XSC), t_*16 + col, chunk_);                       \
        ua[t_] = __builtin_amdgcn_mfma_f32_16x16x32_bf16(a_, PC[kk_],   ua[t_], 0, 0, 0); \
        ga[t_] = __builtin_amdgcn_mfma_f32_16x16x32_bf16(a_, PC[2+kk_], ga[t_], 0, 0, 0); \
      }                                                                        \
    }                                                                          \
    __builtin_amdgcn_s_setprio(0);                                             \
    VMW(8);                                                                    \
    PN[0] = pack8(r0_, r1_); PN[1] = pack8(r2_, r3_);                          \
    PN[2] = pack8(r4_, r5_); PN[3] = pack8(r6_, r7_);                          \
  } while (0)

__global__ __launch_bounds__(256, 2) void k_upgate(
    const unsigned short* __restrict__ xg,
    const float* __restrict__ Wu, const float* __restrict__ Wg,
    const int* __restrict__ counts, const int* __restrict__ basep,
    const int* __restrict__ chtab, const float* __restrict__ wgt,
    unsigned short* __restrict__ hbuf) {
  int bid = blockIdx.x;
  // XCD swizzle + chunk-major decode: the ~7 consecutive blocks on one XCD
  // share the chunk's 1MB x-slab (L2-resident).
  int lb  = (bid & 7) * (NCHMAX*HT_TILES/8) + (bid >> 3);
  int cid = lb / HT_TILES, ht = lb % HT_TILES;
  int ent = chtab[1 + cid];
  if (ent < 0) return;
  int e = ent >> 8, mch = ent & 255;
  int n_e = counts[e], base_e = basep[e], mstart = mch * MCH;

  __shared__ unsigned short xs[2][256*64];   // 32KB each
  __shared__ float swgt[MCH];

  int tid = threadIdx.x;
  int lane = tid & 63, wave = tid >> 6;
  int col = lane & 15;                 // B row (h) within wave's 16
  int kgrp = (lane >> 4) * 8;
  const float* wu_row = Wu + ((size_t)e * DFFN + (size_t)(ht*64 + wave*16 + col)) * DMODEL + kgrp;
  const float* wg_row = Wg + ((size_t)e * DFFN + (size_t)(ht*64 + wave*16 + col)) * DMODEL + kgrp;

  int xrow_lo = lane >> 3;             // 0..7
  int xpc     = lane & 7;
  int swz     = (xpc ^ xrow_lo) * 8;   // row&7 == xrow_lo

  // per-lane global x source bases for the 8 gl16 issues (8-row groups)
  const unsigned short* bx[8];
  #pragma unroll
  for (int i = 0; i < 8; ++i) {
    int row = (i*4 + wave)*8 + xrow_lo;
    int slotr = base_e + mstart + row;
    if (slotr > NSLOT-1) slotr = NSLOT-1;
    bx[i] = xg + (size_t)slotr*DMODEL + swz;
  }

  if (tid < 256) {
    int r = mstart + tid;
    swgt[tid] = (r < n_e) ? wgt[base_e + r] : 0.f;
  }
  LKW0();

  // prologue: W(0) + x(0); retire W(0); pack
  bf16x8 pA[4], pB[4];
  {
    float4 r0 = *(const float4*)(wu_row);
    float4 r1 = *(const float4*)(wu_row + 4);
    float4 r2 = *(const float4*)(wu_row + 32);
    float4 r3 = *(const float4*)(wu_row + 36);
    float4 r4 = *(const float4*)(wg_row);
    float4 r5 = *(const float4*)(wg_row + 4);
    float4 r6 = *(const float4*)(wg_row + 32);
    float4 r7 = *(const float4*)(wg_row + 36);
    #pragma unroll
    for (int i = 0; i < 8; ++i)
      gl16(bx[i], &xs[0][(i*4 + wave)*8*64]);
    VMW(8);   // W(0) retired; x(0) 8 stay in flight
    pA[0] = pack8(r0, r1); pA[1] = pack8(r2, r3);
    pA[2] = pack8(r4, r5); pA[3] = pack8(r6, r7);
  }

  f32x4 ua[16], ga[16];
  #pragma unroll
  for (int t = 0; t < 16; ++t) { f32x4 z = {0.f,0.f,0.f,0.f}; ua[t] = z; ga[t] = z; }

  #pragma unroll 1
  for (int kc = 0; kc < DMODEL/64; kc += 2) {
    UG_STEP(xs[0], xs[1], pA, pB, kc);
    UG_STEP(xs[1], xs[0], pB, pA, kc + 1);
  }

  // epilogue: h = silu(g)*u * gate_weight -> bf16 hbuf
  #pragma unroll
  for (int t = 0; t < 16; ++t)
    #pragma unroll
    for (int r = 0; r < 4; ++r) {
      int ml = t*16 + (lane >> 4)*4 + r;
      if (mstart + ml < n_e) {
        float u = ua[t][r], g = ga[t][r];
        float hv = u * (g / (1.f + expf(-g))) * swgt[ml];
        int slot = base_e + mstart + ml;
        hbuf[(size_t)slot*DFFN + ht*64 + wave*16 + col] = f2b_rne(hv);
      }
    }
}

// ---------------- K5: down-proj; M=256 chunks, 64C per block ----------------
#define DN_STEP(XSC, XSN, PC, PN, KC) do {                                     \
    BAR();                                                                     \
    int kn_ = (KC) + 1; if (kn_ > DFFN/64 - 1) kn_ = DFFN/64 - 1;              \
    const float* pd_ = wd_row + kn_*64;                                        \
    float4 r0_ = *(const float4*)(pd_);                                        \
    float4 r1_ = *(const float4*)(pd_ + 4);                                    \
    float4 r2_ = *(const float4*)(pd_ + 32);                                   \
    float4 r3_ = *(const float4*)(pd_ + 36);                                   \
    _Pragma("unroll")                                                          \
    for (int i_ = 0; i_ < 8; ++i_)                                             \
      gl16(bh[i_] + kn_*64, (XSN) + (i_*4 + wave)*8*64);                       \
    VMW(12);                                                                   \
    BAR();                                                                     \
    __builtin_amdgcn_s_setprio(1);                                             \
    _Pragma("unroll")                                                          \
    for (int kk_ = 0; kk_ < 2; ++kk_) {                                        \
      int chunk_ = kk_*4 + (lane >> 4);                                        \
      _Pragma("unroll")                                                        \
      for (int t_ = 0; t_ < 16; ++t_) {                                        \
        bf16x8 a_ = ld_frag((XSC), t_*16 + col, chunk_);                       \
        acc[t_] = __builtin_amdgcn_mfma_f32_16x16x32_bf16(a_, PC[kk_], acc[t_], 0, 0, 0); \
      }                                                                        \
    }                                                                          \
    __builtin_amdgcn_s_setprio(0);                                             \
    VMW(8);                                                                    \
    PN[0] = pack8(r0_, r1_); PN[1] = pack8(r2_, r3_);                          \
  } while (0)

__global__ __launch_bounds__(256, 2) void k_down(
    const unsigned short* __restrict__ hbuf, const float* __restrict__ Wd,
    const int* __restrict__ counts, const int* __restrict__ basep,
    const int* __restrict__ chtab,
    unsigned short* __restrict__ ypart) {
  int bid = blockIdx.x;
  int lb  = (bid & 7) * (NCHMAX*CT_TILES/8) + (bid >> 3);
  int cid = lb / CT_TILES, ct = lb % CT_TILES;
  int ent = chtab[1 + cid];
  if (ent < 0) return;
  int e = ent >> 8, mch = ent & 255;
  int n_e = counts[e], base_e = basep[e], mstart = mch * MCH;

  __shared__ unsigned short hs[2][256*64];

  int tid = threadIdx.x;
  int lane = tid & 63, wave = tid >> 6;
  int col = lane & 15;
  int kgrp = (lane >> 4) * 8;
  const float* wd_row = Wd + ((size_t)e * DMODEL + (size_t)(ct*64 + wave*16 + col)) * DFFN + kgrp;

  int xrow_lo = lane >> 3;
  int xpc     = lane & 7;
  int swz     = (xpc ^ xrow_lo) * 8;

  const unsigned short* bh[8];
  #pragma unroll
  for (int i = 0; i < 8; ++i) {
    int row = (i*4 + wave)*8 + xrow_lo;
    int slotr = base_e + mstart + row;
    if (slotr > NSLOT-1) slotr = NSLOT-1;
    bh[i] = hbuf + (size_t)slotr*DFFN + swz;
  }

  bf16x8 pA[2], pB[2];
  {
    float4 r0 = *(const float4*)(wd_row);
    float4 r1 = *(const float4*)(wd_row + 4);
    float4 r2 = *(const float4*)(wd_row + 32);
    float4 r3 = *(const float4*)(wd_row + 36);
    #pragma unroll
    for (int i = 0; i < 8; ++i)
      gl16(bh[i], &hs[0][(i*4 + wave)*8*64]);
    VMW(8);
    pA[0] = pack8(r0, r1); pA[1] = pack8(r2, r3);
  }

  f32x4 acc[16];
  #pragma unroll
  for (int t = 0; t < 16; ++t) { f32x4 z = {0.f,0.f,0.f,0.f}; acc[t] = z; }

  #pragma unroll 1
  for (int hc = 0; hc < DFFN/64; hc += 2) {
    DN_STEP(hs[0], hs[1], pA, pB, hc);
    DN_STEP(hs[1], hs[0], pB, pA, hc + 1);
  }

  #pragma unroll
  for (int t = 0; t < 16; ++t)
    #pragma unroll
    for (int r = 0; r < 4; ++r) {
      int ml = t*16 + (lane >> 4)*4 + r;
      if (mstart + ml < n_e) {
        int slot = base_e + mstart + ml;
        ypart[(size_t)slot*DMODEL + ct*64 + wave*16 + col] = f2b_rne(acc[t][r]);
      }
    }
}

// ---------------- K6: combine 4 expert partials per token -> fp32 out ----------------
__global__ void k_combine(const unsigned short* __restrict__ ypart,
                          const int* __restrict__ slotnk, float* __restrict__ out) {
  int n = blockIdx.x, tid = threadIdx.x;
  int c0 = tid * 8;
  float acc[8] = {0.f,0.f,0.f,0.f,0.f,0.f,0.f,0.f};
  #pragma unroll
  for (int k = 0; k < TOPK; ++k) {
    int slot = slotnk[n*TOPK + k];
    uint4 v = *(const uint4*)(ypart + (size_t)slot*DMODEL + c0);
    const unsigned short* p = (const unsigned short*)&v;
    #pragma unroll
    for (int j = 0; j < 8; ++j) acc[j] += b2f(p[j]);
  }
  float4 o0 = {acc[0], acc[1], acc[2], acc[3]};
  float4 o1 = {acc[4], acc[5], acc[6], acc[7]};
  *(float4*)(out + (size_t)n*DMODEL + c0)     = o0;
  *(float4*)(out + (size_t)n*DMODEL + c0 + 4) = o1;
}

// ---------------- launcher ----------------
extern "C" void kernel_launch(void* const* d_in, const int* in_sizes, int n_in,
                              void* d_out, int out_size, void* d_ws, size_t ws_size,
                              hipStream_t stream) {
  const float* x     = (const float*)d_in[0];
  const float* W_up  = (const float*)d_in[1];
  const float* W_gt  = (const float*)d_in[2];
  const float* W_dn  = (const float*)d_in[3];
  const float* g_in  = (const float*)d_in[4];
  float* out = (float*)d_out;
  char* ws = (char*)d_ws;

  int*   counts = (int*)(ws + O_COUNTS);
  int*   basep  = (int*)(ws + O_BASE);
  int*   cursor = (int*)(ws + O_CURSOR);
  int*   chtab  = (int*)(ws + O_CHT);
  int*   topi   = (int*)(ws + O_TOPI);
  float* topw   = (float*)(ws + O_TOPW);
  int*   tok    = (int*)(ws + O_TOK);
  float* wgt    = (float*)(ws + O_WGT);
  int*   slotnk = (int*)(ws + O_SLOTNK);
  unsigned short* xg    = (unsigned short*)(ws + O_XG);
  unsigned short* hbuf  = (unsigned short*)(ws + O_HBUF);
  unsigned short* ypart = xg;   // alias: xg dead after k_upgate

  k_zero   <<<1, 64, 0, stream>>>(counts, cursor);
  k_gate   <<<NTOK, 256, 0, stream>>>(x, g_in, topi, topw, counts);
  k_prefix <<<1, 64, 0, stream>>>(counts, basep, chtab);
  k_scatter<<<4, 256, 0, stream>>>(topi, topw, basep, cursor, tok, wgt, slotnk);
  k_gather <<<NSLOT, 256, 0, stream>>>(x, tok, xg);
  k_upgate <<<NCHMAX*HT_TILES, 256, 0, stream>>>(xg, W_up, W_gt, counts, basep, chtab, wgt, hbuf);
  k_down   <<<NCHMAX*CT_TILES, 256, 0, stream>>>(hbuf, W_dn, counts, basep, chtab, ypart);
  k_combine<<<NTOK, 256, 0, stream>>>(ypart, slotnk, out);
}